// Round 2
// baseline (752.937 us; speedup 1.0000x reference)
//
#include <hip/hip_runtime.h>
#include <hip/hip_bf16.h>

#define NN 100000
#define NE 3200000
#define CI 128
#define NB 4

// SPMM bucketing
#define NBKT 256
#define RPB 391       // ceil(NN / NBKT)
#define P2BLK 1024
#define CHUNK 3125    // NE / P2BLK exactly
#define NSLC 4        // edge-slices per bucket in kSpmm

typedef __attribute__((ext_vector_type(8))) short bf16x8;
typedef __attribute__((ext_vector_type(4))) float f32x4;

__device__ __forceinline__ short f2bf(float f) {
  union { float f; unsigned u; } v; v.f = f;
  unsigned r = v.u + 0x7fffu + ((v.u >> 16) & 1u);  // RNE
  return (short)(r >> 16);
}

// ---------------- Kernel A: w0[n*4+b] = mean_k(key*query), fp32 ----------------
// Thread-per-node, no LDS, no barriers. Per-lane loads are 128B/line-covered so
// HBM/L3 traffic is identical to the staged version; TA divergence hides under
// 2048cy of FMA per chunk. ch-loop kept rolled so loads pipeline a chunk ahead.
__global__ __launch_bounds__(256) void kA(const float* __restrict__ x,
                                          const float* __restrict__ Wk,
                                          const float* __restrict__ Wq,
                                          float* __restrict__ w0) {
  const int b = blockIdx.y;
  const int n = (blockIdx.x << 8) + threadIdx.x;
  if (n >= NN) return;
  const float* xp = x + (size_t)b * NN * CI + (size_t)n * CI;
  float kacc[16], qacc[16];
#pragma unroll
  for (int k = 0; k < 16; ++k) { kacc[k] = 0.f; qacc[k] = 0.f; }
#pragma unroll 1
  for (int ch = 0; ch < 4; ++ch) {
    float xr[32];
#pragma unroll
    for (int i = 0; i < 8; ++i)
      *(float4*)(&xr[4 * i]) = *(const float4*)(xp + (ch << 5) + (i << 2));
    const float* wkp = Wk + (ch << 5);  // uniform -> s_load
    const float* wqp = Wq + (ch << 5);
#pragma unroll
    for (int k = 0; k < 16; ++k) {
      float ka = kacc[k], qa = qacc[k];
#pragma unroll
      for (int c = 0; c < 32; ++c) {
        ka = fmaf(xr[c], wkp[k * CI + c], ka);
        qa = fmaf(xr[c], wqp[k * CI + c], qa);
      }
      kacc[k] = ka; qacc[k] = qa;
    }
  }
  float s = 0.f;
#pragma unroll
  for (int k = 0; k < 16; ++k) s = fmaf(kacc[k], qacc[k], s);
  w0[(n << 2) + b] = s * 0.0625f;
}

// ---------------- kZero: zero w1,w2 (graph-capture-safe, no memset) -----------
__global__ __launch_bounds__(256) void kZero(float4* __restrict__ p, int n4) {
  int i = blockIdx.x * 256 + threadIdx.x;
  if (i < n4) p[i] = make_float4(0.f, 0.f, 0.f, 0.f);
}

// ------------- SPMM phase 1: per-(bucket,block) histogram ----------------------
__global__ __launch_bounds__(256) void kCount(const int* __restrict__ rows,
                                              int* __restrict__ cnt) {
  __shared__ int hist[NBKT];
  const int t = threadIdx.x;
  hist[t] = 0;
  __syncthreads();
  const int e0 = blockIdx.x * CHUNK;
  for (int i = t; i < CHUNK; i += 256) {
    int r = rows[e0 + i];
    atomicAdd(&hist[r / RPB], 1);
  }
  __syncthreads();
  cnt[t * P2BLK + blockIdx.x] = hist[t];
}

// ------------- SPMM phase 2a: per-bucket prefix over P2BLK blocks --------------
__global__ __launch_bounds__(256) void kScan1(int* __restrict__ cnt,
                                              int* __restrict__ tot) {
  __shared__ int s[256];
  const int t = threadIdx.x;
  int* row = cnt + blockIdx.x * P2BLK;
  int4 v = ((int4*)row)[t];               // coalesced, 4 entries/thread
  int a = v.x, b2 = a + v.y, c = b2 + v.z, d = c + v.w;
  s[t] = d;
  __syncthreads();
  for (int off = 1; off < 256; off <<= 1) {
    int add = (t >= off) ? s[t - off] : 0;
    __syncthreads();
    s[t] += add;
    __syncthreads();
  }
  int excl = s[t] - d;                    // exclusive prefix of this thread's 4
  ((int4*)row)[t] = make_int4(excl, excl + a, excl + b2, excl + c);
  if (t == 255) tot[blockIdx.x] = s[255];
}

// ------------- SPMM phase 2b: scan bucket totals -> bktbase --------------------
__global__ __launch_bounds__(256) void kScan2(const int* __restrict__ tot,
                                              int* __restrict__ bktbase) {
  __shared__ int s[256];
  const int t = threadIdx.x;
  int v = tot[t];
  s[t] = v;
  __syncthreads();
  for (int off = 1; off < 256; off <<= 1) {
    int add = (t >= off) ? s[t - off] : 0;
    __syncthreads();
    s[t] += add;
    __syncthreads();
  }
  bktbase[t + 1] = s[t];
  if (t == 0) bktbase[0] = 0;
}

// ------------- SPMM phase 3: scatter into bucket-contiguous (key,val) ----------
__global__ __launch_bounds__(256) void kScatter(const int* __restrict__ rows,
                                                const int* __restrict__ cols,
                                                const float* __restrict__ ev,
                                                const int* __restrict__ cnt,
                                                const int* __restrict__ bktbase,
                                                uint2* __restrict__ kv) {
  __shared__ int cur[NBKT];
  const int t = threadIdx.x;
  cur[t] = bktbase[t] + cnt[t * P2BLK + blockIdx.x];
  __syncthreads();
  const int e0 = blockIdx.x * CHUNK;
  for (int i = t; i < CHUNK; i += 256) {
    int e = e0 + i;
    int r = rows[e], c = cols[e];
    float v = ev[e] * 0.7f;               // fold DECAY once per round's use
    int bkt = r / RPB;
    int rl = r - bkt * RPB;
    int pos = atomicAdd(&cur[bkt], 1);
    kv[pos] = make_uint2(((unsigned)rl << 17) | (unsigned)c, __float_as_uint(v));
  }
}

// ------------- SPMM phase 4: per-(bucket,slice) LDS accumulate (x2 rounds) -----
// Grid (NBKT, NSLC): 4 blocks/CU instead of 1 -> latency of the w[c] gather is
// hidden by TLP. Slices combine via global atomicAdd into pre-zeroed wn.
__global__ __launch_bounds__(512) void kSpmm(const uint2* __restrict__ kv,
                                             const int* __restrict__ bktbase,
                                             const float* __restrict__ wp,
                                             float* __restrict__ wn) {
  __shared__ float acc[RPB * 4];
  const int t = threadIdx.x;
  const int bkt = blockIdx.x;
  for (int i = t; i < RPB * 4; i += 512) acc[i] = 0.f;
  __syncthreads();
  const int e1 = bktbase[bkt + 1];
  for (int e = bktbase[bkt] + (blockIdx.y << 9) + t; e < e1; e += 512 * NSLC) {
    uint2 k2 = kv[e];
    int c = k2.x & 0x1FFFF;
    int rl = k2.x >> 17;
    float v = __uint_as_float(k2.y);
    float4 w = *(const float4*)(wp + (c << 2));
    atomicAdd(&acc[rl * 4 + 0], v * w.x);
    atomicAdd(&acc[rl * 4 + 1], v * w.y);
    atomicAdd(&acc[rl * 4 + 2], v * w.z);
    atomicAdd(&acc[rl * 4 + 3], v * w.w);
  }
  __syncthreads();
  const int base = bkt * RPB;
  const int nw = min(RPB, NN - base) * 4;
  for (int i = t; i < nw; i += 512)
    atomicAdd(&wn[(base << 2) + i], acc[i]);
}

// ------------- Kernel C: values = x*Wv^T (bf16 MFMA) -> *w -> LayerNorm -------
__global__ __launch_bounds__(256) void kC(const float* __restrict__ x,
                                          const float* __restrict__ Wv,
                                          const float* __restrict__ gamma,
                                          const float* __restrict__ beta,
                                          const float* __restrict__ w0,
                                          const float* __restrict__ w1,
                                          const float* __restrict__ w2,
                                          float* __restrict__ out) {
  __shared__ short wv[128 * 136];  // Wv as bf16, row stride 136
  const int t = threadIdx.x;
  const int b = blockIdx.y;
#pragma unroll
  for (int i = 0; i < 16; ++i) {
    int j = (i << 8) + t;
    int row = j >> 5, c4 = j & 31;
    float4 v = *(const float4*)(Wv + row * CI + (c4 << 2));
    short4 s4 = make_short4(f2bf(v.x), f2bf(v.y), f2bf(v.z), f2bf(v.w));
    *(short4*)(&wv[row * 136 + (c4 << 2)]) = s4;
  }
  __syncthreads();
  const int wave = t >> 6, lane = t & 63;
  const int n0 = ((blockIdx.x << 2) + wave) << 4;
  if (n0 >= NN) return;
  const int l15 = lane & 15, quad = lane >> 4;
  const float* xrow = x + (size_t)b * NN * CI + (size_t)(n0 + l15) * CI + (quad << 3);
  bf16x8 af[4];
#pragma unroll
  for (int ck = 0; ck < 4; ++ck) {
    float4 v0 = *(const float4*)(xrow + (ck << 5));
    float4 v1 = *(const float4*)(xrow + (ck << 5) + 4);
    bf16x8 a;
    a[0] = f2bf(v0.x); a[1] = f2bf(v0.y); a[2] = f2bf(v0.z); a[3] = f2bf(v0.w);
    a[4] = f2bf(v1.x); a[5] = f2bf(v1.y); a[6] = f2bf(v1.z); a[7] = f2bf(v1.w);
    af[ck] = a;
  }
  f32x4 acc[8];
#pragma unroll
  for (int o = 0; o < 8; ++o) acc[o] = (f32x4){0.f, 0.f, 0.f, 0.f};
#pragma unroll
  for (int ck = 0; ck < 4; ++ck) {
#pragma unroll
    for (int o = 0; o < 8; ++o) {
      bf16x8 bf = *(const bf16x8*)(&wv[((o << 4) + l15) * 136 + (ck << 5) + (quad << 3)]);
      acc[o] = __builtin_amdgcn_mfma_f32_16x16x32_bf16(af[ck], bf, acc[o], 0, 0, 0);
    }
  }
  float wr[4];
#pragma unroll
  for (int g = 0; g < 4; ++g) {
    int idx = ((n0 + (quad << 2) + g) << 2) + b;
    wr[g] = w0[idx] + w1[idx] + w2[idx];
  }
  float vw[8][4], s1[4] = {0, 0, 0, 0}, s2[4] = {0, 0, 0, 0};
#pragma unroll
  for (int o = 0; o < 8; ++o)
#pragma unroll
    for (int g = 0; g < 4; ++g) {
      float v = acc[o][g] * wr[g];
      vw[o][g] = v;
      s1[g] += v;
      s2[g] = fmaf(v, v, s2[g]);
    }
#pragma unroll
  for (int m = 1; m < 16; m <<= 1)
#pragma unroll
    for (int g = 0; g < 4; ++g) {
      s1[g] += __shfl_xor(s1[g], m, 64);
      s2[g] += __shfl_xor(s2[g], m, 64);
    }
  float mu[4], rs[4];
#pragma unroll
  for (int g = 0; g < 4; ++g) {
    mu[g] = s1[g] * (1.f / 128.f);
    float var = s2[g] * (1.f / 128.f) - mu[g] * mu[g];
    rs[g] = rsqrtf(var + 1e-5f);
  }
  float* ob = out + (size_t)b * NN * CI + (size_t)n0 * CI;
#pragma unroll
  for (int o = 0; o < 8; ++o) {
    int c = (o << 4) + l15;
    float ga = gamma[c], be = beta[c];
#pragma unroll
    for (int g = 0; g < 4; ++g) {
      int r = (quad << 2) + g;
      ob[(size_t)r * CI + c] = (vw[o][g] - mu[g]) * rs[g] * ga + be;
    }
  }
}

extern "C" void kernel_launch(void* const* d_in, const int* in_sizes, int n_in,
                              void* d_out, int out_size, void* d_ws, size_t ws_size,
                              hipStream_t stream) {
  const float* x     = (const float*)d_in[0];
  const float* Wk    = (const float*)d_in[1];
  const float* Wq    = (const float*)d_in[2];
  const float* Wv    = (const float*)d_in[3];
  const float* gamma = (const float*)d_in[4];
  const float* beta  = (const float*)d_in[5];
  const float* ev    = (const float*)d_in[6];
  const int*   ei    = (const int*)d_in[7];  // int64 in source -> int32 on device
  float* out = (float*)d_out;

  // Workspace layout (30.4 MB total):
  //   w0 [NN*4] | w1 [NN*4] | w2 [NN*4] | kv [NE uint2] | bktbase[257] tot[256]
  //   cnt (NBKT*P2BLK = 1MB) ALIASES w2: dead after kScatter, kZero clears it.
  float* w0 = (float*)d_ws;
  float* w1 = w0 + NN * 4;
  float* w2 = w1 + NN * 4;
  uint2* kv = (uint2*)(w2 + NN * 4);
  int* bktbase = (int*)(kv + NE);            // [NBKT+1]
  int* tot = bktbase + NBKT + 1;             // [NBKT]
  int* cnt = (int*)w2;                       // [NBKT*P2BLK], aliased

  const int* rows = ei;
  const int* cols = ei + NE;

  dim3 gA((NN + 255) / 256, NB);
  kA<<<gA, 256, 0, stream>>>(x, Wk, Wq, w0);

  kCount<<<P2BLK, 256, 0, stream>>>(rows, cnt);
  kScan1<<<NBKT, 256, 0, stream>>>(cnt, tot);
  kScan2<<<1, 256, 0, stream>>>(tot, bktbase);
  kScatter<<<P2BLK, 256, 0, stream>>>(rows, cols, ev, cnt, bktbase, kv);

  // zero w1+w2 (kills the cnt alias) before atomic accumulation
  const int n4 = (NN * 4 * 2) / 4;           // 200000 float4s
  kZero<<<(n4 + 255) / 256, 256, 0, stream>>>((float4*)w1, n4);

  dim3 gS(NBKT, NSLC);
  kSpmm<<<gS, 512, 0, stream>>>(kv, bktbase, w0, w1);
  kSpmm<<<gS, 512, 0, stream>>>(kv, bktbase, w1, w2);

  dim3 gC((NN / 16 + 3) / 4, NB);
  kC<<<gC, 256, 0, stream>>>(x, Wv, gamma, beta, w0, w1, w2, out);
}

// Round 4
// 694.344 us; speedup vs baseline: 1.0844x; 1.0844x over previous
//
#include <hip/hip_runtime.h>
#include <hip/hip_bf16.h>

#define NN 100000
#define NE 3200000
#define CI 128
#define NB 4

// SPMM bucketing
#define NBKT 256
#define RPB 391       // ceil(NN / NBKT)
#define P2BLK 1024
#define CHUNK 3125    // NE / P2BLK exactly
#define NSLC 4        // edge-slices per bucket in kSpmm

typedef __attribute__((ext_vector_type(8))) short bf16x8;
typedef __attribute__((ext_vector_type(4))) float f32x4;

__device__ __forceinline__ short f2bf(float f) {
  union { float f; unsigned u; } v; v.f = f;
  unsigned r = v.u + 0x7fffu + ((v.u >> 16) & 1u);  // RNE
  return (short)(r >> 16);
}

// ---------------- Kernel A: w0[n*4+b] = mean_k(key*query), fp32 ----------------
// Round-0 staged structure (proven VALU-minimal codegen: scalar-weight FMAs,
// coalesced block-wide staging, XOR-swizzled LDS) + register double-buffer:
// chunk ch+1's global loads are issued BEFORE chunk ch's 1024 FMAs, and their
// vmcnt drain happens at the NEXT iteration's ds_write — so HBM latency hides
// under ~2048cy of compute instead of serializing at a barrier.
__global__ __launch_bounds__(256) void kA(const float* __restrict__ x,
                                          const float* __restrict__ Wk,
                                          const float* __restrict__ Wq,
                                          float* __restrict__ w0) {
  __shared__ float xs[256 * 32];  // XOR-swizzled: 256 nodes x 32-ch chunk
  const int b = blockIdx.y;
  const int n0 = blockIdx.x << 8;
  const int t = threadIdx.x;
  const float* xb = x + (size_t)b * NN * CI;

  // per-thread staging coordinates (8 float4 quads, coalesced across block)
  int srow[8], sc4[8];
  bool sok[8];
#pragma unroll
  for (int i = 0; i < 8; ++i) {
    int j = (i << 8) + t;
    srow[i] = j >> 3;
    sc4[i] = j & 7;
    sok[i] = (n0 + srow[i]) < NN;
  }

  // prologue: prefetch chunk 0 into registers
  float4 p[8];
#pragma unroll
  for (int i = 0; i < 8; ++i) {
    p[i] = make_float4(0.f, 0.f, 0.f, 0.f);
    if (sok[i]) p[i] = *(const float4*)(xb + (size_t)(n0 + srow[i]) * CI + (sc4[i] << 2));
  }

  float kacc[16], qacc[16];
#pragma unroll
  for (int k = 0; k < 16; ++k) { kacc[k] = 0.f; qacc[k] = 0.f; }

  for (int ch = 0; ch < 4; ++ch) {
    __syncthreads();  // previous chunk's readers done -> xs reusable
#pragma unroll
    for (int i = 0; i < 8; ++i)
      *(float4*)(&xs[(srow[i] << 5) + ((sc4[i] ^ (srow[i] & 7)) << 2)]) = p[i];
    __syncthreads();
    // issue next chunk's loads now; they complete during the FMAs below
    if (ch < 3) {
#pragma unroll
      for (int i = 0; i < 8; ++i) {
        p[i] = make_float4(0.f, 0.f, 0.f, 0.f);
        if (sok[i])
          p[i] = *(const float4*)(xb + (size_t)(n0 + srow[i]) * CI +
                                  ((ch + 1) << 5) + (sc4[i] << 2));
      }
    }
    float xr[32];
#pragma unroll
    for (int j = 0; j < 8; ++j) {
      float4 v = *(const float4*)(&xs[(t << 5) + ((j ^ (t & 7)) << 2)]);
      xr[4 * j + 0] = v.x; xr[4 * j + 1] = v.y; xr[4 * j + 2] = v.z; xr[4 * j + 3] = v.w;
    }
    const float* wkp = Wk + (ch << 5);  // uniform -> s_load
    const float* wqp = Wq + (ch << 5);
#pragma unroll
    for (int k = 0; k < 16; ++k) {
      float ka = kacc[k], qa = qacc[k];
#pragma unroll
      for (int c = 0; c < 32; ++c) {
        ka = fmaf(xr[c], wkp[k * CI + c], ka);
        qa = fmaf(xr[c], wqp[k * CI + c], qa);
      }
      kacc[k] = ka; qacc[k] = qa;
    }
  }
  float s = 0.f;
#pragma unroll
  for (int k = 0; k < 16; ++k) s = fmaf(kacc[k], qacc[k], s);
  int n = n0 + t;
  if (n < NN) w0[(n << 2) + b] = s * 0.0625f;
}

// ---------------- kZero: zero w1,w2 (graph-capture-safe, no memset) -----------
__global__ __launch_bounds__(256) void kZero(float4* __restrict__ p, int n4) {
  int i = blockIdx.x * 256 + threadIdx.x;
  if (i < n4) p[i] = make_float4(0.f, 0.f, 0.f, 0.f);
}

// ------------- SPMM phase 1: per-(bucket,block) histogram ----------------------
__global__ __launch_bounds__(256) void kCount(const int* __restrict__ rows,
                                              int* __restrict__ cnt) {
  __shared__ int hist[NBKT];
  const int t = threadIdx.x;
  hist[t] = 0;
  __syncthreads();
  const int e0 = blockIdx.x * CHUNK;
  for (int i = t; i < CHUNK; i += 256) {
    int r = rows[e0 + i];
    atomicAdd(&hist[r / RPB], 1);
  }
  __syncthreads();
  cnt[t * P2BLK + blockIdx.x] = hist[t];
}

// ------------- SPMM phase 2a: per-bucket prefix over P2BLK blocks --------------
__global__ __launch_bounds__(256) void kScan1(int* __restrict__ cnt,
                                              int* __restrict__ tot) {
  __shared__ int s[256];
  const int t = threadIdx.x;
  int* row = cnt + blockIdx.x * P2BLK;
  int4 v = ((int4*)row)[t];               // coalesced, 4 entries/thread
  int a = v.x, b2 = a + v.y, c = b2 + v.z, d = c + v.w;
  s[t] = d;
  __syncthreads();
  for (int off = 1; off < 256; off <<= 1) {
    int add = (t >= off) ? s[t - off] : 0;
    __syncthreads();
    s[t] += add;
    __syncthreads();
  }
  int excl = s[t] - d;                    // exclusive prefix of this thread's 4
  ((int4*)row)[t] = make_int4(excl, excl + a, excl + b2, excl + c);
  if (t == 255) tot[blockIdx.x] = s[255];
}

// ------------- SPMM phase 2b: scan bucket totals -> bktbase --------------------
__global__ __launch_bounds__(256) void kScan2(const int* __restrict__ tot,
                                              int* __restrict__ bktbase) {
  __shared__ int s[256];
  const int t = threadIdx.x;
  int v = tot[t];
  s[t] = v;
  __syncthreads();
  for (int off = 1; off < 256; off <<= 1) {
    int add = (t >= off) ? s[t - off] : 0;
    __syncthreads();
    s[t] += add;
    __syncthreads();
  }
  bktbase[t + 1] = s[t];
  if (t == 0) bktbase[0] = 0;
}

// ------------- SPMM phase 3: scatter into bucket-contiguous (key,val) ----------
__global__ __launch_bounds__(256) void kScatter(const int* __restrict__ rows,
                                                const int* __restrict__ cols,
                                                const float* __restrict__ ev,
                                                const int* __restrict__ cnt,
                                                const int* __restrict__ bktbase,
                                                uint2* __restrict__ kv) {
  __shared__ int cur[NBKT];
  const int t = threadIdx.x;
  cur[t] = bktbase[t] + cnt[t * P2BLK + blockIdx.x];
  __syncthreads();
  const int e0 = blockIdx.x * CHUNK;
  for (int i = t; i < CHUNK; i += 256) {
    int e = e0 + i;
    int r = rows[e], c = cols[e];
    float v = ev[e] * 0.7f;               // fold DECAY once per round's use
    int bkt = r / RPB;
    int rl = r - bkt * RPB;
    int pos = atomicAdd(&cur[bkt], 1);
    kv[pos] = make_uint2(((unsigned)rl << 17) | (unsigned)c, __float_as_uint(v));
  }
}

// ------------- SPMM phase 4: per-(bucket,slice) LDS accumulate (x2 rounds) -----
// Grid (NBKT, NSLC): 4 blocks/CU instead of 1 -> latency of the w[c] gather is
// hidden by TLP. Slices combine via global atomicAdd into pre-zeroed wn.
__global__ __launch_bounds__(512) void kSpmm(const uint2* __restrict__ kv,
                                             const int* __restrict__ bktbase,
                                             const float* __restrict__ wp,
                                             float* __restrict__ wn) {
  __shared__ float acc[RPB * 4];
  const int t = threadIdx.x;
  const int bkt = blockIdx.x;
  for (int i = t; i < RPB * 4; i += 512) acc[i] = 0.f;
  __syncthreads();
  const int e1 = bktbase[bkt + 1];
  for (int e = bktbase[bkt] + (blockIdx.y << 9) + t; e < e1; e += 512 * NSLC) {
    uint2 k2 = kv[e];
    int c = k2.x & 0x1FFFF;
    int rl = k2.x >> 17;
    float v = __uint_as_float(k2.y);
    float4 w = *(const float4*)(wp + (c << 2));
    atomicAdd(&acc[rl * 4 + 0], v * w.x);
    atomicAdd(&acc[rl * 4 + 1], v * w.y);
    atomicAdd(&acc[rl * 4 + 2], v * w.z);
    atomicAdd(&acc[rl * 4 + 3], v * w.w);
  }
  __syncthreads();
  const int base = bkt * RPB;
  const int nw = min(RPB, NN - base) * 4;
  for (int i = t; i < nw; i += 512)
    atomicAdd(&wn[(base << 2) + i], acc[i]);
}

// ------------- Kernel C: values = x*Wv^T (bf16 MFMA) -> *w -> LayerNorm -------
__global__ __launch_bounds__(256) void kC(const float* __restrict__ x,
                                          const float* __restrict__ Wv,
                                          const float* __restrict__ gamma,
                                          const float* __restrict__ beta,
                                          const float* __restrict__ w0,
                                          const float* __restrict__ w1,
                                          const float* __restrict__ w2,
                                          float* __restrict__ out) {
  __shared__ short wv[128 * 136];  // Wv as bf16, row stride 136
  const int t = threadIdx.x;
  const int b = blockIdx.y;
#pragma unroll
  for (int i = 0; i < 16; ++i) {
    int j = (i << 8) + t;
    int row = j >> 5, c4 = j & 31;
    float4 v = *(const float4*)(Wv + row * CI + (c4 << 2));
    short4 s4 = make_short4(f2bf(v.x), f2bf(v.y), f2bf(v.z), f2bf(v.w));
    *(short4*)(&wv[row * 136 + (c4 << 2)]) = s4;
  }
  __syncthreads();
  const int wave = t >> 6, lane = t & 63;
  const int n0 = ((blockIdx.x << 2) + wave) << 4;
  if (n0 >= NN) return;
  const int l15 = lane & 15, quad = lane >> 4;
  const float* xrow = x + (size_t)b * NN * CI + (size_t)(n0 + l15) * CI + (quad << 3);
  bf16x8 af[4];
#pragma unroll
  for (int ck = 0; ck < 4; ++ck) {
    float4 v0 = *(const float4*)(xrow + (ck << 5));
    float4 v1 = *(const float4*)(xrow + (ck << 5) + 4);
    bf16x8 a;
    a[0] = f2bf(v0.x); a[1] = f2bf(v0.y); a[2] = f2bf(v0.z); a[3] = f2bf(v0.w);
    a[4] = f2bf(v1.x); a[5] = f2bf(v1.y); a[6] = f2bf(v1.z); a[7] = f2bf(v1.w);
    af[ck] = a;
  }
  f32x4 acc[8];
#pragma unroll
  for (int o = 0; o < 8; ++o) acc[o] = (f32x4){0.f, 0.f, 0.f, 0.f};
#pragma unroll
  for (int ck = 0; ck < 4; ++ck) {
#pragma unroll
    for (int o = 0; o < 8; ++o) {
      bf16x8 bf = *(const bf16x8*)(&wv[((o << 4) + l15) * 136 + (ck << 5) + (quad << 3)]);
      acc[o] = __builtin_amdgcn_mfma_f32_16x16x32_bf16(af[ck], bf, acc[o], 0, 0, 0);
    }
  }
  float wr[4];
#pragma unroll
  for (int g = 0; g < 4; ++g) {
    int idx = ((n0 + (quad << 2) + g) << 2) + b;
    wr[g] = w0[idx] + w1[idx] + w2[idx];
  }
  float vw[8][4], s1[4] = {0, 0, 0, 0}, s2[4] = {0, 0, 0, 0};
#pragma unroll
  for (int o = 0; o < 8; ++o)
#pragma unroll
    for (int g = 0; g < 4; ++g) {
      float v = acc[o][g] * wr[g];
      vw[o][g] = v;
      s1[g] += v;
      s2[g] = fmaf(v, v, s2[g]);
    }
#pragma unroll
  for (int m = 1; m < 16; m <<= 1)
#pragma unroll
    for (int g = 0; g < 4; ++g) {
      s1[g] += __shfl_xor(s1[g], m, 64);
      s2[g] += __shfl_xor(s2[g], m, 64);
    }
  float mu[4], rs[4];
#pragma unroll
  for (int g = 0; g < 4; ++g) {
    mu[g] = s1[g] * (1.f / 128.f);
    float var = s2[g] * (1.f / 128.f) - mu[g] * mu[g];
    rs[g] = rsqrtf(var + 1e-5f);
  }
  float* ob = out + (size_t)b * NN * CI + (size_t)n0 * CI;
#pragma unroll
  for (int o = 0; o < 8; ++o) {
    int c = (o << 4) + l15;
    float ga = gamma[c], be = beta[c];
#pragma unroll
    for (int g = 0; g < 4; ++g) {
      int r = (quad << 2) + g;
      ob[(size_t)r * CI + c] = (vw[o][g] - mu[g]) * rs[g] * ga + be;
    }
  }
}

extern "C" void kernel_launch(void* const* d_in, const int* in_sizes, int n_in,
                              void* d_out, int out_size, void* d_ws, size_t ws_size,
                              hipStream_t stream) {
  const float* x     = (const float*)d_in[0];
  const float* Wk    = (const float*)d_in[1];
  const float* Wq    = (const float*)d_in[2];
  const float* Wv    = (const float*)d_in[3];
  const float* gamma = (const float*)d_in[4];
  const float* beta  = (const float*)d_in[5];
  const float* ev    = (const float*)d_in[6];
  const int*   ei    = (const int*)d_in[7];  // int64 in source -> int32 on device
  float* out = (float*)d_out;

  // Workspace layout (30.4 MB total):
  //   w0 [NN*4] | w1 [NN*4] | w2 [NN*4] | kv [NE uint2] | bktbase[257] tot[256]
  //   cnt (NBKT*P2BLK = 1MB) ALIASES w2: dead after kScatter, kZero clears it.
  float* w0 = (float*)d_ws;
  float* w1 = w0 + NN * 4;
  float* w2 = w1 + NN * 4;
  uint2* kv = (uint2*)(w2 + NN * 4);
  int* bktbase = (int*)(kv + NE);            // [NBKT+1]
  int* tot = bktbase + NBKT + 1;             // [NBKT]
  int* cnt = (int*)w2;                       // [NBKT*P2BLK], aliased

  const int* rows = ei;
  const int* cols = ei + NE;

  dim3 gA((NN + 255) / 256, NB);
  kA<<<gA, 256, 0, stream>>>(x, Wk, Wq, w0);

  kCount<<<P2BLK, 256, 0, stream>>>(rows, cnt);
  kScan1<<<NBKT, 256, 0, stream>>>(cnt, tot);
  kScan2<<<1, 256, 0, stream>>>(tot, bktbase);
  kScatter<<<P2BLK, 256, 0, stream>>>(rows, cols, ev, cnt, bktbase, kv);

  // zero w1+w2 (kills the cnt alias) before atomic accumulation
  const int n4 = (NN * 4 * 2) / 4;           // 200000 float4s
  kZero<<<(n4 + 255) / 256, 256, 0, stream>>>((float4*)w1, n4);

  dim3 gS(NBKT, NSLC);
  kSpmm<<<gS, 512, 0, stream>>>(kv, bktbase, w0, w1);
  kSpmm<<<gS, 512, 0, stream>>>(kv, bktbase, w1, w2);

  dim3 gC((NN / 16 + 3) / 4, NB);
  kC<<<gC, 256, 0, stream>>>(x, Wv, gamma, beta, w0, w1, w2, out);
}